// Round 1
// baseline (2836.765 us; speedup 1.0000x reference)
//
#include <hip/hip_runtime.h>
#include <hip/hip_bf16.h>
#include <stdint.h>

#define HID 1024
#define G4H 4096
#define BATCH 4096
#define TSTEPS 28
#define DIN 28
#define KTOT 1056   // 1024 (h) + 28 (x_t) + 4 zero pad -> 33 * 32
#define NKEY 8

typedef __attribute__((ext_vector_type(8))) __bf16 b16x8;
typedef __attribute__((ext_vector_type(4))) float f32x4;
typedef __attribute__((address_space(1))) unsigned int u32_g;
typedef __attribute__((address_space(3))) unsigned int u32_l;

__device__ __forceinline__ void async16(const __hip_bfloat16* g, __hip_bfloat16* l) {
  __builtin_amdgcn_global_load_lds((u32_g*)g, (u32_l*)l, 16, 0, 0);
}

__device__ __forceinline__ float sigmoidf_(float x) { return 1.f / (1.f + __expf(-x)); }
__device__ __forceinline__ float tanhfast_(float x) { return 2.f / (1.f + __expf(-2.f * x)) - 1.f; }

// ---- one-time: build Wt[n][k] bf16 (n in [0,4096), k in [0,1056)); also zero hk/ck ----
__global__ __launch_bounds__(256) void prep_weights(
    const float* __restrict__ W_hh, const float* __restrict__ W_ih,
    __hip_bfloat16* __restrict__ Wt, float* __restrict__ kstate) {
  __shared__ float tile[64][65];
  const int k0 = blockIdx.x * 64, n0 = blockIdx.y * 64;
  const int tid = threadIdx.x;
  const int fid = (blockIdx.y * gridDim.x + blockIdx.x) * 256 + tid;
  if (fid < 2 * NKEY * HID) kstate[fid] = 0.f;   // hk, ck (contiguous)
  for (int i = tid; i < 4096; i += 256) {
    int kk = i >> 6, nn = i & 63;
    int k = k0 + kk;
    float v = 0.f;
    if (k < HID) v = W_hh[k * G4H + n0 + nn];
    else if (k < HID + DIN) v = W_ih[(k - HID) * G4H + n0 + nn];
    tile[kk][nn] = v;
  }
  __syncthreads();
  for (int i = tid; i < 4096; i += 256) {
    int nn = i >> 6, kk = i & 63;
    int k = k0 + kk;
    if (k < KTOT) Wt[(size_t)(n0 + nn) * KTOT + k] = __float2bfloat16(tile[kk][nn]);
  }
}

// ---- key pass (fp32 exact, tiny) ----
__global__ __launch_bounds__(256) void key_gates(
    const float* __restrict__ W_hh, const float* __restrict__ W_ih,
    const float* __restrict__ key_seq, const float* __restrict__ hk,
    float* __restrict__ Gk, int t) {
  __shared__ float sh[NKEY * HID];
  __shared__ float sx[NKEY * DIN];
  __shared__ float sred[4][NKEY][64];
  const int tid = threadIdx.x;
  for (int i = tid; i < NKEY * HID; i += 256) sh[i] = hk[i];
  if (tid < NKEY * DIN) {
    int k = tid / DIN, d = tid % DIN;
    sx[tid] = key_seq[k * (TSTEPS * DIN) + t * DIN + d];
  }
  __syncthreads();
  const int jj = tid & 63, part = tid >> 6;
  const int j = blockIdx.x * 64 + jj;
  float acc[NKEY];
#pragma unroll
  for (int k = 0; k < NKEY; ++k) acc[k] = 0.f;
  const int h0 = part * 256;
  for (int h = h0; h < h0 + 256; ++h) {
    float w = W_hh[h * G4H + j];
#pragma unroll
    for (int k = 0; k < NKEY; ++k) acc[k] += sh[k * HID + h] * w;
  }
  const int d0 = part * 7;
  for (int d = d0; d < d0 + 7; ++d) {
    float w = W_ih[d * G4H + j];
#pragma unroll
    for (int k = 0; k < NKEY; ++k) acc[k] += sx[k * DIN + d] * w;
  }
#pragma unroll
  for (int k = 0; k < NKEY; ++k) sred[part][k][jj] = acc[k];
  __syncthreads();
  if (part == 0) {
#pragma unroll
    for (int k = 0; k < NKEY; ++k) {
      float v = sred[0][k][jj] + sred[1][k][jj] + sred[2][k][jj] + sred[3][k][jj];
      Gk[k * G4H + j] = v;
    }
  }
}

__global__ __launch_bounds__(256) void key_update(
    const float* __restrict__ Gk, const float* __restrict__ bias,
    float* __restrict__ hk, float* __restrict__ ck) {
  int idx = blockIdx.x * 256 + threadIdx.x;  // 8192
  int k = idx >> 10, j = idx & (HID - 1);
  float gi = Gk[k * G4H + j] + bias[j];
  float gf = Gk[k * G4H + HID + j] + bias[HID + j];
  float gg = Gk[k * G4H + 2 * HID + j] + bias[2 * HID + j];
  float go = Gk[k * G4H + 3 * HID + j] + bias[3 * HID + j];
  float cv = sigmoidf_(gf) * ck[idx] + sigmoidf_(gi) * tanhfast_(gg);
  ck[idx] = cv;
  hk[idx] = sigmoidf_(go) * tanhfast_(cv);
}

__global__ __launch_bounds__(256) void key_mean(
    const float* __restrict__ hk, const float* __restrict__ ck,
    float* __restrict__ h0, float* __restrict__ c0) {
  int j = blockIdx.x * 256 + threadIdx.x;  // 1024
  float sh_ = 0.f, sc_ = 0.f;
#pragma unroll
  for (int k = 0; k < NKEY; ++k) { sh_ += hk[k * HID + j]; sc_ += ck[k * HID + j]; }
  h0[j] = sh_ * (1.f / NKEY);
  c0[j] = sc_ * (1.f / NKEY);
}

// ---- main pass init: A = [bf16(h0) | bf16(x[:,0,:]) | 0], c = c0 ----
__global__ __launch_bounds__(256) void main_init(
    const float* __restrict__ h0, const float* __restrict__ c0,
    const float* __restrict__ x, __hip_bfloat16* __restrict__ A,
    float* __restrict__ c) {
  int idx = blockIdx.x * 256 + threadIdx.x;  // 4096*1056
  int b = idx / KTOT, col = idx - b * KTOT;
  if (col < HID) {
    A[idx] = __float2bfloat16(h0[col]);
    c[b * HID + col] = c0[col];
  } else if (col < HID + DIN) {
    A[idx] = __float2bfloat16(x[b * (TSTEPS * DIN) + (col - HID)]);
  } else {
    A[idx] = __float2bfloat16(0.f);
  }
}

// ---- G = A[4096,1056] * Wt[4096,1056]^T  (m97-style 128x128 tile, bf16 MFMA) ----
__global__ __launch_bounds__(256) void gemm_gates(
    const __hip_bfloat16* __restrict__ Amat, const __hip_bfloat16* __restrict__ Bt,
    float* __restrict__ G) {
  __shared__ alignas(16) __hip_bfloat16 sA[128 * 32];
  __shared__ alignas(16) __hip_bfloat16 sB[128 * 32];
  const int tid = threadIdx.x;
  const int lane = tid & 63, wave = tid >> 6;
  const int wr = wave >> 1, wc = wave & 1;
  const int brow = blockIdx.x * 128, bcol = blockIdx.y * 128;
  f32x4 acc[4][4] = {};
  const int srow = tid >> 2;
  const int sk = (tid & 3) * 8;
  const __hip_bfloat16* ga = Amat + (size_t)(brow + srow) * KTOT + sk;
  const __hip_bfloat16* gb = Bt + (size_t)(bcol + srow) * KTOT + sk;
  const int lrow = lane & 15, kq = lane >> 4;
  const b16x8* sAv = (const b16x8*)sA;
  const b16x8* sBv = (const b16x8*)sB;

  for (int kt = 0; kt < KTOT; kt += 32) {
    async16(ga + kt, sA + tid * 8);
    async16(ga + (size_t)64 * KTOT + kt, sA + tid * 8 + 2048);
    async16(gb + kt, sB + tid * 8);
    async16(gb + (size_t)64 * KTOT + kt, sB + tid * 8 + 2048);
    __syncthreads();
    b16x8 af[4], bfr[4];
#pragma unroll
    for (int m = 0; m < 4; ++m) af[m] = sAv[(wr * 64 + m * 16 + lrow) * 4 + kq];
#pragma unroll
    for (int n = 0; n < 4; ++n) bfr[n] = sBv[(wc * 64 + n * 16 + lrow) * 4 + kq];
#pragma unroll
    for (int m = 0; m < 4; ++m)
#pragma unroll
      for (int n = 0; n < 4; ++n)
        acc[m][n] = __builtin_amdgcn_mfma_f32_16x16x32_bf16(af[m], bfr[n], acc[m][n], 0, 0, 0);
    __syncthreads();
  }
#pragma unroll
  for (int m = 0; m < 4; ++m) {
    const int row0 = brow + wr * 64 + m * 16 + (lane >> 4) * 4;
#pragma unroll
    for (int n = 0; n < 4; ++n) {
      const int col = bcol + wc * 64 + n * 16 + (lane & 15);
#pragma unroll
      for (int r = 0; r < 4; ++r)
        G[(size_t)(row0 + r) * G4H + col] = acc[m][n][r];
    }
  }
}

// ---- gate nonlinearities + state update; writes h back into A (bf16) + next x slice ----
__global__ __launch_bounds__(256) void main_update(
    const float* __restrict__ G, const float* __restrict__ bias,
    float* __restrict__ c, __hip_bfloat16* __restrict__ A,
    const float* __restrict__ x, float* __restrict__ hfin,
    int t) {
  int idx = blockIdx.x * 256 + threadIdx.x;  // 4096*1024
  int b = idx >> 10, j = idx & (HID - 1);
  const float* g = G + (size_t)b * G4H + j;
  float gi = g[0] + bias[j];
  float gf = g[HID] + bias[HID + j];
  float gg = g[2 * HID] + bias[2 * HID + j];
  float go = g[3 * HID] + bias[3 * HID + j];
  float cv = sigmoidf_(gf) * c[idx] + sigmoidf_(gi) * tanhfast_(gg);
  c[idx] = cv;
  float h = sigmoidf_(go) * tanhfast_(cv);
  A[(size_t)b * KTOT + j] = __float2bfloat16(h);
  if (j < DIN && t + 1 < TSTEPS)
    A[(size_t)b * KTOT + HID + j] = __float2bfloat16(x[b * (TSTEPS * DIN) + (t + 1) * DIN + j]);
  if (t == TSTEPS - 1) hfin[idx] = h;
}

// ---- out = hfin @ W_cls + b_cls ----
__global__ __launch_bounds__(256) void classifier(
    const float* __restrict__ hfin, const float* __restrict__ W_cls,
    const float* __restrict__ b_cls, float* __restrict__ out) {
  __shared__ float sw[HID * 10];
  __shared__ float sred[10][257];
  const int b = blockIdx.x, tid = threadIdx.x;
  for (int i = tid; i < HID * 10; i += 256) sw[i] = W_cls[i];
  __syncthreads();
  float acc[10];
#pragma unroll
  for (int cls = 0; cls < 10; ++cls) acc[cls] = 0.f;
  for (int j = tid; j < HID; j += 256) {
    float hv = hfin[(size_t)b * HID + j];
#pragma unroll
    for (int cls = 0; cls < 10; ++cls) acc[cls] += hv * sw[j * 10 + cls];
  }
#pragma unroll
  for (int cls = 0; cls < 10; ++cls) sred[cls][tid] = acc[cls];
  __syncthreads();
  for (int off = 128; off > 0; off >>= 1) {
    if (tid < off)
#pragma unroll
      for (int cls = 0; cls < 10; ++cls) sred[cls][tid] += sred[cls][tid + off];
    __syncthreads();
  }
  if (tid < 10) out[b * 10 + tid] = sred[tid][0] + b_cls[tid];
}

extern "C" void kernel_launch(void* const* d_in, const int* in_sizes, int n_in,
                              void* d_out, int out_size, void* d_ws, size_t ws_size,
                              hipStream_t stream) {
  const float* x      = (const float*)d_in[0];
  const float* keyseq = (const float*)d_in[1];
  const float* W_ih   = (const float*)d_in[2];
  const float* W_hh   = (const float*)d_in[3];
  const float* bias   = (const float*)d_in[4];
  const float* W_cls  = (const float*)d_in[5];
  const float* b_cls  = (const float*)d_in[6];
  float* out = (float*)d_out;
  (void)in_sizes; (void)n_in; (void)out_size; (void)ws_size;

  char* p = (char*)d_ws;
  auto alloc = [&](size_t bytes) { char* r = p; p += (bytes + 255) & ~(size_t)255; return r; };
  __hip_bfloat16* Wt = (__hip_bfloat16*)alloc((size_t)G4H * KTOT * 2);
  __hip_bfloat16* A  = (__hip_bfloat16*)alloc((size_t)BATCH * KTOT * 2);
  float* G    = (float*)alloc((size_t)BATCH * G4H * 4);
  float* c    = (float*)alloc((size_t)BATCH * HID * 4);
  float* hfin = (float*)alloc((size_t)BATCH * HID * 4);
  float* hk   = (float*)alloc((size_t)NKEY * HID * 4);   // hk then ck contiguous
  float* ck   = (float*)alloc((size_t)NKEY * HID * 4);
  float* Gk   = (float*)alloc((size_t)NKEY * G4H * 4);
  float* h0   = (float*)alloc((size_t)HID * 4);
  float* c0   = (float*)alloc((size_t)HID * 4);

  prep_weights<<<dim3(17, 64), 256, 0, stream>>>(W_hh, W_ih, Wt, hk);

  for (int t = 0; t < TSTEPS; ++t) {
    key_gates<<<64, 256, 0, stream>>>(W_hh, W_ih, keyseq, hk, Gk, t);
    key_update<<<32, 256, 0, stream>>>(Gk, bias, hk, ck);
  }
  key_mean<<<4, 256, 0, stream>>>(hk, ck, h0, c0);
  main_init<<<(BATCH * KTOT) / 256, 256, 0, stream>>>(h0, c0, x, A, c);

  for (int t = 0; t < TSTEPS; ++t) {
    gemm_gates<<<dim3(32, 32), 256, 0, stream>>>(A, Wt, G);
    main_update<<<(BATCH * HID) / 256, 256, 0, stream>>>(G, bias, c, A, x, hfin, t);
  }
  classifier<<<BATCH, 256, 0, stream>>>(hfin, W_cls, b_cls, out);
}

// Round 2
// 2107.782 us; speedup vs baseline: 1.3459x; 1.3459x over previous
//
#include <hip/hip_runtime.h>
#include <hip/hip_bf16.h>
#include <stdint.h>

#define HID 1024
#define G4H 4096
#define BATCH 4096
#define TSTEPS 28
#define DIN 28
#define KTOT 1056   // 1024 (h) + 28 (x_t) + 4 zero pad -> 33 * 32
#define NKEY 8

typedef __attribute__((ext_vector_type(8))) __bf16 b16x8;
typedef __attribute__((ext_vector_type(4))) __bf16 b16x4;
typedef __attribute__((ext_vector_type(4))) float f32x4;
typedef __attribute__((address_space(1))) unsigned int u32_g;
typedef __attribute__((address_space(3))) unsigned int u32_l;

__device__ __forceinline__ void async16(const __hip_bfloat16* g, __hip_bfloat16* l) {
  __builtin_amdgcn_global_load_lds((u32_g*)g, (u32_l*)l, 16, 0, 0);
}

__device__ __forceinline__ float sigmoidf_(float x) { return 1.f / (1.f + __expf(-x)); }
__device__ __forceinline__ float tanhfast_(float x) { return 2.f / (1.f + __expf(-2.f * x)) - 1.f; }

// ---- one-time: build Wt[n][k] bf16 (gate-blocked n, k in [0,1056)); zero hk0+ck ----
__global__ __launch_bounds__(256) void prep_weights(
    const float* __restrict__ W_hh, const float* __restrict__ W_ih,
    __hip_bfloat16* __restrict__ Wt, float* __restrict__ kstate) {
  __shared__ float tile[64][65];
  const int k0 = blockIdx.x * 64, n0 = blockIdx.y * 64;
  const int tid = threadIdx.x;
  const int fid = (blockIdx.y * gridDim.x + blockIdx.x) * 256 + tid;
  if (fid < 2 * NKEY * HID) kstate[fid] = 0.f;   // hk0, ck (contiguous)
  for (int i = tid; i < 4096; i += 256) {
    int kk = i >> 6, nn = i & 63;
    int k = k0 + kk;
    float v = 0.f;
    if (k < HID) v = W_hh[k * G4H + n0 + nn];
    else if (k < HID + DIN) v = W_ih[(k - HID) * G4H + n0 + nn];
    tile[kk][nn] = v;
  }
  __syncthreads();
  for (int i = tid; i < 4096; i += 256) {
    int nn = i >> 6, kk = i & 63;
    int k = k0 + kk;
    if (k < KTOT) Wt[(size_t)(n0 + nn) * KTOT + k] = __float2bfloat16(tile[kk][nn]);
  }
}

// ---- key pass: one fused step (gates + cell update), bf16 weights, fp32 math ----
__global__ __launch_bounds__(256) void key_step(
    const __hip_bfloat16* __restrict__ Wt, const float* __restrict__ key_seq,
    const float* __restrict__ bias, const float* __restrict__ hk_in,
    float* __restrict__ hk_out, float* __restrict__ ck, int t) {
  __shared__ float sh[NKEY][KTOT];        // 33.8 KB: [h | x_t | 0pad]
  __shared__ float sred[32][8][8];        // [gate*8+jj][kpart][key]
  const int tid = threadIdx.x;
#pragma unroll
  for (int key = 0; key < NKEY; ++key)
    for (int k = tid; k < HID; k += 256) sh[key][k] = hk_in[key * HID + k];
  for (int i = tid; i < NKEY * 32; i += 256) {
    int key = i >> 5, d = i & 31;
    sh[key][HID + d] = (d < DIN) ? key_seq[key * (TSTEPS * DIN) + t * DIN + d] : 0.f;
  }
  __syncthreads();
  const int rowIdx = tid >> 3;          // 0..31 = gate*8 + jj
  const int kpart = tid & 7;
  const int gate = rowIdx >> 3, jj = rowIdx & 7;
  const int j0 = blockIdx.x * 8;
  const int n = gate * HID + j0 + jj;
  const __hip_bfloat16* wrow = Wt + (size_t)n * KTOT + kpart * 132;
  const int kb = kpart * 132;
  float acc[NKEY];
#pragma unroll
  for (int key = 0; key < NKEY; ++key) acc[key] = 0.f;
  for (int kk = 0; kk < 132; kk += 4) {
    b16x4 wv = *(const b16x4*)(wrow + kk);
    float w0 = (float)wv[0], w1 = (float)wv[1], w2 = (float)wv[2], w3 = (float)wv[3];
#pragma unroll
    for (int key = 0; key < NKEY; ++key) {
      const float* s = &sh[key][kb + kk];
      acc[key] += w0 * s[0] + w1 * s[1] + w2 * s[2] + w3 * s[3];
    }
  }
#pragma unroll
  for (int key = 0; key < NKEY; ++key) sred[rowIdx][kpart][key] = acc[key];
  __syncthreads();
  if (tid < 64) {
    int key = tid >> 3, j2 = tid & 7;
    float g[4];
#pragma unroll
    for (int gg = 0; gg < 4; ++gg) {
      float s = 0.f;
#pragma unroll
      for (int p = 0; p < 8; ++p) s += sred[gg * 8 + j2][p][key];
      g[gg] = s + bias[gg * HID + j0 + j2];
    }
    size_t ci = (size_t)key * HID + j0 + j2;
    float cv = sigmoidf_(g[1]) * ck[ci] + sigmoidf_(g[0]) * tanhfast_(g[2]);
    ck[ci] = cv;
    hk_out[ci] = sigmoidf_(g[3]) * tanhfast_(cv);
  }
}

__global__ __launch_bounds__(256) void key_mean(
    const float* __restrict__ hk, const float* __restrict__ ck,
    float* __restrict__ h0, float* __restrict__ c0) {
  int j = blockIdx.x * 256 + threadIdx.x;  // 1024
  float sh_ = 0.f, sc_ = 0.f;
#pragma unroll
  for (int k = 0; k < NKEY; ++k) { sh_ += hk[k * HID + j]; sc_ += ck[k * HID + j]; }
  h0[j] = sh_ * (1.f / NKEY);
  c0[j] = sc_ * (1.f / NKEY);
}

// ---- main pass init: A0 = [bf16(h0) | bf16(x[:,0,:]) | 0], A1 pad = 0, c = c0 ----
__global__ __launch_bounds__(256) void main_init(
    const float* __restrict__ h0, const float* __restrict__ c0,
    const float* __restrict__ x, __hip_bfloat16* __restrict__ A0,
    __hip_bfloat16* __restrict__ A1, float* __restrict__ c) {
  int idx = blockIdx.x * 256 + threadIdx.x;  // 4096*1056
  int b = idx / KTOT, col = idx - b * KTOT;
  if (col < HID) {
    A0[idx] = __float2bfloat16(h0[col]);
    c[b * HID + col] = c0[col];
  } else if (col < HID + DIN) {
    A0[idx] = __float2bfloat16(x[b * (TSTEPS * DIN) + (col - HID)]);
  } else {
    A0[idx] = __float2bfloat16(0.f);
    A1[idx] = __float2bfloat16(0.f);
  }
}

// ---- fused GEMM + LSTM cell: one launch per timestep ----
// Block: 128 rows x 32 j-cols x 4 gates. Grid dim3(32 jtiles, 32 mtiles) so
// flat%8 == jtile%8 -> each XCD sees 4 jtiles (~1MB of Wt, L2-resident).
__global__ __launch_bounds__(256, 2) void gemm_lstm(
    const __hip_bfloat16* __restrict__ Ain, const __hip_bfloat16* __restrict__ Wt,
    const float* __restrict__ bias, float* __restrict__ cst,
    __hip_bfloat16* __restrict__ Aout, const float* __restrict__ x,
    float* __restrict__ hfin, int t) {
  __shared__ alignas(16) __hip_bfloat16 sA[2][128 * 32];      // 2 x 8KB
  __shared__ alignas(16) __hip_bfloat16 sB[2][4 * 32 * 32];   // 2 x 8KB (4 gate strips)
  const int tid = threadIdx.x;
  const int lane = tid & 63, wave = tid >> 6;
  const int wr = wave >> 1, wc = wave & 1;
  const int jt = blockIdx.x, mt = blockIdx.y;
  const int brow = mt * 128, j0 = jt * 32;
  const int lrow = lane & 15, kq = lane >> 4;

  // staging: LDS dest linear (granule = tid, tid+256); source k-quad swizzled
  const int kqs = (tid & 3) ^ ((tid >> 3) & 3);
  const int sArow = tid >> 2;              // 0..63 (+64 for second load)
  const int sBstrip = tid >> 7;            // gate 0/1 (+2 for second load)
  const int sBrow = (tid >> 2) & 31;
  const __hip_bfloat16* gA0 = Ain + (size_t)(brow + sArow) * KTOT + kqs * 8;
  const __hip_bfloat16* gA1 = gA0 + (size_t)64 * KTOT;
  const __hip_bfloat16* gB0 = Wt + (size_t)(sBstrip * HID + j0 + sBrow) * KTOT + kqs * 8;
  const __hip_bfloat16* gB1 = gB0 + (size_t)2 * HID * KTOT;

  // fragment-read granule indices (swizzled), constant across K-steps
  int iA[4];
#pragma unroll
  for (int m = 0; m < 4; ++m) {
    int u = (wr * 64 + m * 16 + lrow) * 4 + kq;
    iA[m] = u ^ ((u >> 3) & 3);
  }
  int uB = (wc * 16 + lrow) * 4 + kq;
  const int iB = uB ^ ((uB >> 3) & 3);

  f32x4 acc[4][4] = {};   // [gate][m]

  // prologue stage
  async16(gA0, &sA[0][tid * 8]);
  async16(gA1, &sA[0][2048 + tid * 8]);
  async16(gB0, &sB[0][tid * 8]);
  async16(gB1, &sB[0][2048 + tid * 8]);
  __syncthreads();

  for (int it = 0; it < 33; ++it) {
    if (it < 32) {
      const int kt = (it + 1) * 32;
      const int nb = (it + 1) & 1;
      async16(gA0 + kt, &sA[nb][tid * 8]);
      async16(gA1 + kt, &sA[nb][2048 + tid * 8]);
      async16(gB0 + kt, &sB[nb][tid * 8]);
      async16(gB1 + kt, &sB[nb][2048 + tid * 8]);
    }
    const b16x8* sAv = (const b16x8*)sA[it & 1];
    const b16x8* sBv = (const b16x8*)sB[it & 1];
    b16x8 af[4];
#pragma unroll
    for (int m = 0; m < 4; ++m) af[m] = sAv[iA[m]];
    __builtin_amdgcn_s_setprio(1);
#pragma unroll
    for (int g = 0; g < 4; ++g) {
      b16x8 bfr = sBv[g * 128 + iB];
#pragma unroll
      for (int m = 0; m < 4; ++m)
        acc[g][m] = __builtin_amdgcn_mfma_f32_16x16x32_bf16(af[m], bfr, acc[g][m], 0, 0, 0);
    }
    __builtin_amdgcn_s_setprio(0);
    __syncthreads();   // drains staged loads (vmcnt) + frag reads (lgkm)
  }

  // fused LSTM cell epilogue
  const int jcol = j0 + wc * 16 + lrow;
  const float b_i = bias[jcol], b_f = bias[HID + jcol];
  const float b_g = bias[2 * HID + jcol], b_o = bias[3 * HID + jcol];
#pragma unroll
  for (int m = 0; m < 4; ++m) {
    const int row0 = brow + wr * 64 + m * 16 + (lane >> 4) * 4;
#pragma unroll
    for (int r = 0; r < 4; ++r) {
      const int row = row0 + r;
      const size_t ci = (size_t)row * HID + jcol;
      float gi = acc[0][m][r] + b_i;
      float gf = acc[1][m][r] + b_f;
      float gg = acc[2][m][r] + b_g;
      float go = acc[3][m][r] + b_o;
      float cv = sigmoidf_(gf) * cst[ci] + sigmoidf_(gi) * tanhfast_(gg);
      cst[ci] = cv;
      float h = sigmoidf_(go) * tanhfast_(cv);
      Aout[(size_t)row * KTOT + jcol] = __float2bfloat16(h);
      if (t == TSTEPS - 1) hfin[ci] = h;
    }
  }
  // inject next x slice (jt==0 blocks own their 128 rows)
  if (jt == 0 && t + 1 < TSTEPS) {
    for (int i = tid; i < 128 * DIN; i += 256) {
      int rr = i / DIN, d = i - rr * DIN;
      Aout[(size_t)(brow + rr) * KTOT + HID + d] =
          __float2bfloat16(x[(size_t)(brow + rr) * (TSTEPS * DIN) + (t + 1) * DIN + d]);
    }
  }
}

// ---- out = hfin @ W_cls + b_cls ----
__global__ __launch_bounds__(256) void classifier(
    const float* __restrict__ hfin, const float* __restrict__ W_cls,
    const float* __restrict__ b_cls, float* __restrict__ out) {
  __shared__ float sw[HID * 10];
  __shared__ float sred[10][257];
  const int b = blockIdx.x, tid = threadIdx.x;
  for (int i = tid; i < HID * 10; i += 256) sw[i] = W_cls[i];
  __syncthreads();
  float acc[10];
#pragma unroll
  for (int cls = 0; cls < 10; ++cls) acc[cls] = 0.f;
  for (int j = tid; j < HID; j += 256) {
    float hv = hfin[(size_t)b * HID + j];
#pragma unroll
    for (int cls = 0; cls < 10; ++cls) acc[cls] += hv * sw[j * 10 + cls];
  }
#pragma unroll
  for (int cls = 0; cls < 10; ++cls) sred[cls][tid] = acc[cls];
  __syncthreads();
  for (int off = 128; off > 0; off >>= 1) {
    if (tid < off)
#pragma unroll
      for (int cls = 0; cls < 10; ++cls) sred[cls][tid] += sred[cls][tid + off];
    __syncthreads();
  }
  if (tid < 10) out[b * 10 + tid] = sred[tid][0] + b_cls[tid];
}

extern "C" void kernel_launch(void* const* d_in, const int* in_sizes, int n_in,
                              void* d_out, int out_size, void* d_ws, size_t ws_size,
                              hipStream_t stream) {
  const float* x      = (const float*)d_in[0];
  const float* keyseq = (const float*)d_in[1];
  const float* W_ih   = (const float*)d_in[2];
  const float* W_hh   = (const float*)d_in[3];
  const float* bias   = (const float*)d_in[4];
  const float* W_cls  = (const float*)d_in[5];
  const float* b_cls  = (const float*)d_in[6];
  float* out = (float*)d_out;
  (void)in_sizes; (void)n_in; (void)out_size; (void)ws_size;

  char* p = (char*)d_ws;
  auto alloc = [&](size_t bytes) { char* r = p; p += (bytes + 255) & ~(size_t)255; return r; };
  __hip_bfloat16* Wt = (__hip_bfloat16*)alloc((size_t)G4H * KTOT * 2);
  __hip_bfloat16* A0 = (__hip_bfloat16*)alloc((size_t)BATCH * KTOT * 2);
  __hip_bfloat16* A1 = (__hip_bfloat16*)alloc((size_t)BATCH * KTOT * 2);
  float* c    = (float*)alloc((size_t)BATCH * HID * 4);
  float* hfin = (float*)alloc((size_t)BATCH * HID * 4);
  float* hk0  = (float*)alloc((size_t)NKEY * HID * 4);   // hk0 then ck contiguous (zeroed together)
  float* ck   = (float*)alloc((size_t)NKEY * HID * 4);
  float* hk1  = (float*)alloc((size_t)NKEY * HID * 4);
  float* h0   = (float*)alloc((size_t)HID * 4);
  float* c0   = (float*)alloc((size_t)HID * 4);

  prep_weights<<<dim3(17, 64), 256, 0, stream>>>(W_hh, W_ih, Wt, hk0);

  float* kbuf[2] = {hk0, hk1};
  for (int t = 0; t < TSTEPS; ++t)
    key_step<<<128, 256, 0, stream>>>(Wt, keyseq, bias, kbuf[t & 1], kbuf[(t + 1) & 1], ck, t);
  key_mean<<<4, 256, 0, stream>>>(hk0, ck, h0, c0);   // final state lands in kbuf[0]

  main_init<<<(BATCH * KTOT) / 256, 256, 0, stream>>>(h0, c0, x, A0, A1, c);

  __hip_bfloat16* Ab[2] = {A0, A1};
  for (int t = 0; t < TSTEPS; ++t)
    gemm_lstm<<<dim3(32, 32), 256, 0, stream>>>(Ab[t & 1], Wt, bias, c,
                                                Ab[(t + 1) & 1], x, hfin, t);
  classifier<<<BATCH, 256, 0, stream>>>(hfin, W_cls, b_cls, out);
}